// Round 1
// baseline (379.716 us; speedup 1.0000x reference)
//
#include <hip/hip_runtime.h>
#include <hip/hip_bf16.h>
#include <stdint.h>

typedef __attribute__((ext_vector_type(8))) short short8;
typedef __attribute__((ext_vector_type(4))) float f32x4;

__device__ __forceinline__ float bf2f(short u) {
  return __uint_as_float(((unsigned)(unsigned short)u) << 16);
}
__device__ __forceinline__ short f2bf(float f) {
  unsigned x = __float_as_uint(f);
  unsigned r = (x + 0x7fffu + ((x >> 16) & 1u)) >> 16;
  return (short)r;
}

__device__ __forceinline__ void gload_lds16(const short* g, short* l) {
  __builtin_amdgcn_global_load_lds(
      (const __attribute__((address_space(1))) void*)g,
      (__attribute__((address_space(3))) void*)l, 16, 0, 0);
}

// ---------------- cast x (f32 -> bf16), 8 elems/thread ----------------
__global__ void cast_x_bf16(const float* __restrict__ in, short* __restrict__ out, int n8) {
  int i = blockIdx.x * blockDim.x + threadIdx.x;
  if (i >= n8) return;
  const float4* p = (const float4*)in + (size_t)i * 2;
  float4 a = p[0], b = p[1];
  short8 o;
  o[0] = f2bf(a.x); o[1] = f2bf(a.y); o[2] = f2bf(a.z); o[3] = f2bf(a.w);
  o[4] = f2bf(b.x); o[5] = f2bf(b.y); o[6] = f2bf(b.z); o[7] = f2bf(b.w);
  *((short8*)out + i) = o;
}

// ------------- transpose + cast: out[row_off + c][r] = in[r][c] -------------
// grid (C/32, R/32), block (32,8). Dims are multiples of 32.
__global__ void transpose_cast(const float* __restrict__ in, int R, int C,
                               short* __restrict__ out, int row_off, int ldo) {
  __shared__ float tile[32][33];
  int c0 = blockIdx.x * 32, r0 = blockIdx.y * 32;
  int tx = threadIdx.x, ty = threadIdx.y;
#pragma unroll
  for (int i = 0; i < 4; ++i)
    tile[ty + i * 8][tx] = in[(size_t)(r0 + ty + i * 8) * C + (c0 + tx)];
  __syncthreads();
#pragma unroll
  for (int i = 0; i < 4; ++i)
    out[(size_t)(row_off + c0 + ty + i * 8) * ldo + (r0 + tx)] =
        f2bf(tile[tx][ty + i * 8]);
}

// ---------------- GEMM: C = A[M,K] * Bt[N,K]^T  (bf16 in, bf16 or f32+bias out)
// 128x128 tile, BK=64, 4 waves (2x2), 16x16x32 MFMA, global_load_lds staging.
template <int OUT_F32>
__global__ __launch_bounds__(256)
void gemm_bt(const short* __restrict__ A, const short* __restrict__ Bt,
             int M, int N, int K, int ldc,
             short* __restrict__ outb, float* __restrict__ outf,
             const float* __restrict__ bias) {
  __shared__ short As[128 * 64];
  __shared__ short Bs[128 * 64];
  const int tid = threadIdx.x, lane = tid & 63;
  const int wr = tid >> 7, wc = (tid >> 6) & 1;
  const int l15 = lane & 15, l4 = lane >> 4;
  const int m0 = blockIdx.y * 128, n0 = blockIdx.x * 128;
  f32x4 acc[4][4] = {};
  for (int k0 = 0; k0 < K; k0 += 64) {
#pragma unroll
    for (int iss = 0; iss < 4; ++iss) {
      int c = iss * 256 + tid;
      int row = c >> 3, q = c & 7;
      gload_lds16(A + (size_t)(m0 + row) * K + k0 + q * 8,
                  As + iss * 2048 + (tid & 192) * 8);
      gload_lds16(Bt + (size_t)(n0 + row) * K + k0 + q * 8,
                  Bs + iss * 2048 + (tid & 192) * 8);
    }
    __syncthreads();
#pragma unroll
    for (int kk = 0; kk < 2; ++kk) {
      short8 a[4], b[4];
#pragma unroll
      for (int mi = 0; mi < 4; ++mi)
        a[mi] = *(const short8*)(As + (wr * 64 + mi * 16 + l15) * 64 + kk * 32 + l4 * 8);
#pragma unroll
      for (int ni = 0; ni < 4; ++ni)
        b[ni] = *(const short8*)(Bs + (wc * 64 + ni * 16 + l15) * 64 + kk * 32 + l4 * 8);
#pragma unroll
      for (int mi = 0; mi < 4; ++mi)
#pragma unroll
        for (int ni = 0; ni < 4; ++ni)
          acc[mi][ni] = __builtin_amdgcn_mfma_f32_16x16x32_bf16(a[mi], b[ni], acc[mi][ni], 0, 0, 0);
    }
    __syncthreads();
  }
#pragma unroll
  for (int mi = 0; mi < 4; ++mi)
#pragma unroll
    for (int ni = 0; ni < 4; ++ni)
#pragma unroll
      for (int r = 0; r < 4; ++r) {
        int row = m0 + wr * 64 + mi * 16 + l4 * 4 + r;
        int col = n0 + wc * 64 + ni * 16 + l15;
        if (OUT_F32)
          outf[(size_t)row * ldc + col] = acc[mi][ni][r] + bias[col];
        else
          outb[(size_t)row * ldc + col] = f2bf(acc[mi][ni][r]);
      }
}

// ---------------- RoPE in-place on qkv (q heads + single k head) ----------------
__global__ void rope_kernel(short* __restrict__ qkv, const int* __restrict__ segpos,
                            int nheads, int hd, int ld) {
  const int row = blockIdx.x;
  const float pos = (float)segpos[row];
  short* base = qkv + (size_t)row * ld;
  const int quarter = hd >> 2;                 // 32
  const int npairs_q = nheads * quarter;       // 512
  const int total = npairs_q + quarter;        // + k pairs
  for (int p = threadIdx.x; p < total; p += blockDim.x) {
    int i, off;
    if (p < npairs_q) { off = (p >> 5) * hd; i = p & 31; }
    else              { off = nheads * hd;  i = p - npairs_q; }
    // inv_freq = 10000^(-i/quarter)
    float ang = pos * exp2f(-(float)i * (13.287712379549449f / (float)quarter));
    float s, c;
    sincosf(ang, &s, &c);
    float a = bf2f(base[off + i]);
    float b = bf2f(base[off + quarter + i]);
    base[off + i]           = f2bf(a * c - b * s);
    base[off + quarter + i] = f2bf(b * c + a * s);
  }
}

// ---------------- windowed causal flash attention (MQA), H=128 ----------------
// grid (T/64, B*nheads), 256 threads (4 waves x 16 q-rows).
__global__ __launch_bounds__(256)
void attn_kernel(const short* __restrict__ qkv, short* __restrict__ enc,
                 const int* __restrict__ wsz_p, int T, int nheads) {
  const int window = wsz_p[0];
  const int qt = blockIdx.x;
  const int bh = blockIdx.y;
  const int b = bh / nheads, n = bh % nheads;
  const int tid = threadIdx.x, lane = tid & 63, w = tid >> 6;
  const int l15 = lane & 15, l4 = lane >> 4;
  const int q0 = qt * 64;
  const size_t rowbase = (size_t)b * T;
  const int LD = nheads * 128 + 256;           // qkv row stride (2304)
  const int kcol = nheads * 128;               // k column offset
  const float CC = 0.08838834764831845f * 1.4426950408889634f; // rsqrt(128)*log2(e)

  __shared__ short Ks[64 * 128];               // XOR-swizzled rows
  __shared__ short Vt[128 * 64];               // V^T, XOR-swizzled rows
  __shared__ short Pl[4][16 * 72];             // per-wave P scratch (padded)

  short8 qf[4];
  {
    const short* qptr = qkv + (rowbase + q0 + w * 16 + l15) * LD + n * 128 + l4 * 8;
#pragma unroll
    for (int kk = 0; kk < 4; ++kk) qf[kk] = *(const short8*)(qptr + kk * 32);
  }
  f32x4 o[8] = {};
  float mrow[4], lrow[4];
#pragma unroll
  for (int r = 0; r < 4; ++r) { mrow[r] = -1e30f; lrow[r] = 0.f; }

  int st_lo = q0 - window; if (st_lo < 0) st_lo = 0; st_lo >>= 6;
  const int st_hi = q0 >> 6;
  for (int st = st_lo; st <= st_hi; ++st) {
    const int s0 = st * 64;
    // stage K (row-major, swizzled): 64x128 bf16
#pragma unroll
    for (int it = 0; it < 4; ++it) {
      int c = it * 256 + tid;
      int r = c >> 4, col8 = (c & 15) * 8;
      short8 kv = *(const short8*)(qkv + (rowbase + s0 + r) * LD + kcol + col8);
      int byt = (r * 256 + col8 * 2) ^ ((r & 7) << 4);
      *(short8*)((char*)Ks + byt) = kv;
    }
    // stage V^T (columns gathered from global, swizzled rows)
#pragma unroll
    for (int it = 0; it < 4; ++it) {
      int c = it * 256 + tid;
      int h = c & 127, s8 = (c >> 7) * 8;
      const short* vp = qkv + (rowbase + s0 + s8) * LD + kcol + 128 + h;
      short8 vv;
#pragma unroll
      for (int j = 0; j < 8; ++j) vv[j] = vp[(size_t)j * LD];
      int byt = (h * 128 + s8 * 2) ^ ((h & 7) << 4);
      *(short8*)((char*)Vt + byt) = vv;
    }
    __syncthreads();
    // S = Q K^T  (4 col-subtiles of 16)
    f32x4 sacc[4];
#pragma unroll
    for (int si = 0; si < 4; ++si) {
      f32x4 acc = {};
      int srow = si * 16 + l15;
#pragma unroll
      for (int kk = 0; kk < 4; ++kk) {
        int byt = (srow * 256 + (kk * 32 + l4 * 8) * 2) ^ ((srow & 7) << 4);
        short8 kf = *(const short8*)((const char*)Ks + byt);
        acc = __builtin_amdgcn_mfma_f32_16x16x32_bf16(qf[kk], kf, acc, 0, 0, 0);
      }
      sacc[si] = acc;
    }
    // mask + online softmax
    const int trow0 = q0 + w * 16 + l4 * 4;
    float mt[4];
#pragma unroll
    for (int r = 0; r < 4; ++r) mt[r] = -1e30f;
#pragma unroll
    for (int si = 0; si < 4; ++si) {
      int s = s0 + si * 16 + l15;
#pragma unroll
      for (int r = 0; r < 4; ++r) {
        int t = trow0 + r;
        float v = (s <= t && t <= s + window) ? sacc[si][r] : -1e30f;
        sacc[si][r] = v;
        mt[r] = fmaxf(mt[r], v);
      }
    }
#pragma unroll
    for (int r = 0; r < 4; ++r)
#pragma unroll
      for (int off = 1; off < 16; off <<= 1)
        mt[r] = fmaxf(mt[r], __shfl_xor(mt[r], off));
    float fac[4], psum[4];
#pragma unroll
    for (int r = 0; r < 4; ++r) {
      float mnew = fmaxf(mrow[r], mt[r]);
      fac[r] = exp2f((mrow[r] - mnew) * CC);
      mrow[r] = mnew;
      psum[r] = 0.f;
    }
#pragma unroll
    for (int si = 0; si < 4; ++si)
#pragma unroll
      for (int r = 0; r < 4; ++r) {
        float p = exp2f((sacc[si][r] - mrow[r]) * CC);
        psum[r] += p;
        Pl[w][(l4 * 4 + r) * 72 + si * 16 + l15] = f2bf(p);
      }
#pragma unroll
    for (int r = 0; r < 4; ++r) {
#pragma unroll
      for (int off = 1; off < 16; off <<= 1)
        psum[r] += __shfl_xor(psum[r], off);
      lrow[r] = lrow[r] * fac[r] + psum[r];
    }
#pragma unroll
    for (int nt = 0; nt < 8; ++nt)
#pragma unroll
      for (int r = 0; r < 4; ++r) o[nt][r] *= fac[r];
    // PV
#pragma unroll
    for (int kk = 0; kk < 2; ++kk) {
      short8 pf = *(const short8*)(&Pl[w][l15 * 72 + kk * 32 + l4 * 8]);
#pragma unroll
      for (int nt = 0; nt < 8; ++nt) {
        int h = nt * 16 + l15;
        int byt = (h * 128 + (kk * 32 + l4 * 8) * 2) ^ ((h & 7) << 4);
        short8 vf = *(const short8*)((const char*)Vt + byt);
        o[nt] = __builtin_amdgcn_mfma_f32_16x16x32_bf16(pf, vf, o[nt], 0, 0, 0);
      }
    }
    __syncthreads();
  }
  // epilogue: normalize + store bf16
#pragma unroll
  for (int nt = 0; nt < 8; ++nt)
#pragma unroll
    for (int r = 0; r < 4; ++r) {
      size_t row = rowbase + q0 + w * 16 + l4 * 4 + r;
      int col = n * 128 + nt * 16 + l15;
      enc[row * (size_t)(nheads * 128) + col] = f2bf(o[nt][r] / lrow[r]);
    }
}

extern "C" void kernel_launch(void* const* d_in, const int* in_sizes, int n_in,
                              void* d_out, int out_size, void* d_ws, size_t ws_size,
                              hipStream_t stream) {
  const float* x     = (const float*)d_in[0];
  const float* w_q   = (const float*)d_in[1];
  const float* w_k   = (const float*)d_in[2];
  const float* w_v   = (const float*)d_in[3];
  const float* w_out = (const float*)d_in[4];
  const float* b_out = (const float*)d_in[5];
  const int* segpos  = (const int*)d_in[6];
  const int* wsz     = (const int*)d_in[8];
  float* out = (float*)d_out;

  const int BT = in_sizes[6];          // B*T = 4096
  const int W  = in_sizes[5];          // 2048
  const int H  = in_sizes[2] / W;      // 128
  const int NH = W / H;                // 16
  const int T  = 2048;                 // harness instance (B=2, T=2048)
  const int NQKV = W + 2 * H;          // 2304

  char* ws = (char*)d_ws;
  short* xb    = (short*)ws;                                       // BT*W
  short* wqkvT = (short*)(ws + (size_t)BT * W * 2);                // NQKV*W
  short* woutT = (short*)(ws + (size_t)(BT * W + NQKV * W) * 2);   // W*W
  short* qkv   = (short*)(ws + (size_t)(BT * W + NQKV * W + W * W) * 2); // BT*NQKV
  short* enc   = xb;  // reuse after GEMM1 consumed x

  int n8 = BT * W / 8;
  cast_x_bf16<<<(n8 + 255) / 256, 256, 0, stream>>>(x, xb, n8);

  dim3 tb(32, 8);
  transpose_cast<<<dim3(W / 32, W / 32), tb, 0, stream>>>(w_q, W, W, wqkvT, 0, W);
  transpose_cast<<<dim3(H / 32, W / 32), tb, 0, stream>>>(w_k, W, H, wqkvT, W, W);
  transpose_cast<<<dim3(H / 32, W / 32), tb, 0, stream>>>(w_v, W, H, wqkvT, W + H, W);
  transpose_cast<<<dim3(W / 32, W / 32), tb, 0, stream>>>(w_out, W, W, woutT, 0, W);

  gemm_bt<0><<<dim3(NQKV / 128, BT / 128), 256, 0, stream>>>(
      xb, wqkvT, BT, NQKV, W, NQKV, qkv, nullptr, nullptr);

  rope_kernel<<<BT, 256, 0, stream>>>(qkv, segpos, NH, H, NQKV);

  attn_kernel<<<dim3(T / 64, (BT / T) * NH), 256, 0, stream>>>(qkv, enc, wsz, T, NH);

  gemm_bt<1><<<dim3(W / 128, BT / 128), 256, 0, stream>>>(
      enc, woutT, BT, W, W, W, nullptr, out, b_out);
}